// Round 7
// baseline (300.098 us; speedup 1.0000x reference)
//
#include <hip/hip_runtime.h>
#include <hip/hip_bf16.h>

typedef __attribute__((ext_vector_type(4))) float f32x4;
typedef __attribute__((ext_vector_type(8))) short short8;
typedef __attribute__((ext_vector_type(4))) short short4v;
using bf16 = __hip_bfloat16;

__device__ __forceinline__ short f2bf(float x) {
  union { bf16 h; short s; } u;
  u.h = __float2bfloat16(x);
  return u.s;
}

__device__ __forceinline__ void gload16(const void* g, void* l) {
  __builtin_amdgcn_global_load_lds(
      (const __attribute__((address_space(1))) void*)g,
      (__attribute__((address_space(3))) void*)l, 16, 0, 0);
}

// ---------------- fp32 -> bf16 conversion (grid-stride) ----------------
__global__ void cvt_f32_to_bf16(const float* __restrict__ src,
                                bf16* __restrict__ dst, int n4) {
  int i = blockIdx.x * blockDim.x + threadIdx.x;
  const int stride = gridDim.x * blockDim.x;
  for (; i < n4; i += stride) {
    f32x4 v = ((const f32x4*)src)[i];
    short4v o;
    o[0] = f2bf(v[0]); o[1] = f2bf(v[1]); o[2] = f2bf(v[2]); o[3] = f2bf(v[3]);
    ((short4v*)dst)[i] = o;
  }
}

// ------- 256x256 GEMM, BK=32, 4-buffer rotation, 4-quadrant phases -------
// C = A * B^T + bias. K fixed 512 = 16 K-tiles, fully unrolled. 512 threads =
// 8 waves (2M x 4N), per-wave output 128x64, acc[8][4]. LDS 128 KiB.
//
// Residency ledger (r4-proven, unchanged): stage tile t+3 into buf (t+3)&3
// during tile t (that buf's last reads finished before the end-of-(t-1)
// close barrier); single counted s_waitcnt vmcnt(8) (= 2 tiles in flight) +
// s_barrier at each tile close; tail V(4)@13, V(0)@14.
//
// NEW (8-phase port, m201/T3+T4 rhythm): the 32 MFMA per tile are split into
// 4 C-quadrant phases, each {ds_read only this quadrant's new fragments ||
// stage 1 sub-tile of t+3 -> s_barrier -> setprio'd 8-MFMA cluster}.
// Reads target the stable cur buffer; stages target a buffer nobody reads
// this tile -> mid-tile barriers are pure scheduling gates (no new hazards).
template<bool OUT_BF16>
__global__ __launch_bounds__(512) void gemm_bt(
    const bf16* __restrict__ A, int lda,
    const bf16* __restrict__ B, int ldb,
    const float* __restrict__ bias,
    void* __restrict__ Cv, int ldc, int nbx)
{
  __shared__ __align__(16) bf16 lA[4][256 * 32];
  __shared__ __align__(16) bf16 lB[4][256 * 32];

  const int tid  = threadIdx.x;
  const int lane = tid & 63;
  const int w    = tid >> 6;   // wave 0..7
  const int wr   = w >> 2;     // M half: rows wr*128..+127
  const int wc   = w & 3;      // N quarter: rows wc*64..+63
  const int l15  = lane & 15;
  const int kg   = lane >> 4;                    // k-slot 0..3
  const int po   = (kg ^ ((l15 >> 1) & 3)) * 8;  // swizzled read col (elems)

  const int nwg = gridDim.x;
  const int dd  = blockIdx.x;
  const int wid = (dd & 7) * (nwg >> 3) + (dd >> 3);  // bijective XCD swizzle
  const size_t bm = (size_t)(wid / nbx) * 256;
  const size_t bn = (size_t)(wid % nbx) * 256;

  // Staging: round h covers rows h*128..+127; thread -> row h*128+w*16+(lane>>2),
  // 16B at source col-slot (lane&3)^((lane>>3)&3) [= logical^(row>>1)&3].
  // LDS dest is wave-uniform base + lane*16B (linear).
  const int srow = w * 16 + (lane >> 2);
  const int scol = ((lane & 3) ^ ((lane >> 3) & 3)) * 8;
  const int wofs = w * 512;

  const bf16* Ab = A + (bm + srow) * lda + scol;
  const bf16* Bb = B + (bn + srow) * ldb + scol;

  f32x4 acc[8][4];
#pragma unroll
  for (int i = 0; i < 8; ++i)
#pragma unroll
    for (int j = 0; j < 4; ++j) acc[i][j] = (f32x4)0.f;

  short8 af[8], bq[4];

#define SA(buf, h, kt) gload16(Ab + (size_t)((h) * 128) * lda + (kt), \
                               &lA[buf][(h) * 4096 + wofs])
#define SB(buf, h, kt) gload16(Bb + (size_t)((h) * 128) * ldb + (kt), \
                               &lB[buf][(h) * 4096 + wofs])

#define RDA(buf, mi) af[mi] = *(const short8*)&lA[buf][(wr * 128 + (mi) * 16 + l15) * 32 + po]
#define RDB(buf, ni) bq[ni] = *(const short8*)&lB[buf][(wc * 64 + (ni) * 16 + l15) * 32 + po]

  // 8 MFMA for quadrant (mibase..+3) x (nibase..+1), setprio-wrapped
#define MMQ(mibase, nibase) do { \
    __builtin_amdgcn_s_setprio(1); \
    _Pragma("unroll") for (int mi = 0; mi < 4; ++mi) \
    _Pragma("unroll") for (int ni = 0; ni < 2; ++ni) \
      acc[(mibase) + mi][(nibase) + ni] = __builtin_amdgcn_mfma_f32_16x16x32_bf16( \
          bq[(nibase) + ni], af[(mibase) + mi], acc[(mibase) + mi][(nibase) + ni], 0, 0, 0); \
    __builtin_amdgcn_s_setprio(0); \
    __builtin_amdgcn_sched_barrier(0); } while (0)

#define GATE() do { \
    __builtin_amdgcn_s_barrier(); \
    __builtin_amdgcn_sched_barrier(0); } while (0)

#define CLOSE_V(N) do { \
    __builtin_amdgcn_sched_barrier(0); \
    asm volatile("s_waitcnt vmcnt(" #N ")" ::: "memory"); \
    __builtin_amdgcn_sched_barrier(0); \
    __builtin_amdgcn_s_barrier(); \
    __builtin_amdgcn_sched_barrier(0); \
    asm volatile("" ::: "memory"); } while (0)

  // prologue: stage tiles 0,1,2 (4 loads each); t0,t1 resident, t2 in flight
  SA(0, 0, 0);  SA(0, 1, 0);  SB(0, 0, 0);  SB(0, 1, 0);
  SA(1, 0, 32); SA(1, 1, 32); SB(1, 0, 32); SB(1, 1, 32);
  SA(2, 0, 64); SA(2, 1, 64); SB(2, 0, 64); SB(2, 1, 64);
  CLOSE_V(8);

#pragma unroll
  for (int t = 0; t < 16; ++t) {
    const int cur = t & 3, pf = (t + 3) & 3;
    const int kt3 = (t + 3) * 32;

    // P1: quadrant (mi0-3, ni0-1); reads A0-frags + B0-frags; stages A(h0)
    RDA(cur, 0); RDA(cur, 1); RDA(cur, 2); RDA(cur, 3);
    RDB(cur, 0); RDB(cur, 1);
    if (t < 13) SA(pf, 0, kt3);
    GATE();
    MMQ(0, 0);

    // P2: (mi0-3, ni2-3); reads B1-frags; stages B(h0)
    RDB(cur, 2); RDB(cur, 3);
    if (t < 13) SB(pf, 0, kt3);
    GATE();
    MMQ(0, 2);

    // P3: (mi4-7, ni2-3); reads A1-frags; stages A(h1)
    RDA(cur, 4); RDA(cur, 5); RDA(cur, 6); RDA(cur, 7);
    if (t < 13) SA(pf, 1, kt3);
    GATE();
    MMQ(4, 2);

    // P4: (mi4-7, ni0-1); register-only; stages B(h1); tile close
    if (t < 13) SB(pf, 1, kt3);
    GATE();
    MMQ(4, 0);

    if (t <= 12)      CLOSE_V(8);
    else if (t == 13) CLOSE_V(4);
    else if (t == 14) CLOSE_V(0);
    // t == 15: fall through to epilogue
  }

#undef SA
#undef SB
#undef RDA
#undef RDB
#undef MMQ
#undef GATE
#undef CLOSE_V

  // Epilogue: lane holds m = bm+wr*128+mi*16+l15, n = bn+wc*64+ni*16+kg*4+j
#pragma unroll
  for (int mi = 0; mi < 8; ++mi) {
    const size_t mrow = bm + wr * 128 + mi * 16 + l15;
#pragma unroll
    for (int ni = 0; ni < 4; ++ni) {
      const int nb = (int)bn + wc * 64 + ni * 16 + kg * 4;
      f32x4 bv = *(const f32x4*)&bias[nb];
      f32x4 r = acc[mi][ni] + bv;
      if constexpr (OUT_BF16) {
        short4v o;
        o[0] = f2bf(r[0]); o[1] = f2bf(r[1]); o[2] = f2bf(r[2]); o[3] = f2bf(r[3]);
        *(short4v*)((bf16*)Cv + mrow * ldc + nb) = o;
      } else {
        *(f32x4*)((float*)Cv + mrow * ldc + nb) = r;
      }
    }
  }
}

// ------------- fused block-attention + output GEMM -------------
// One block per 64 qkv rows (4 attention 16-blocks). 512 threads = 8 waves.
// Phase A: wave w handles 16-row sub-block (w>>1) x heads (w&1)*4..+3.
//   Swapped-PV MFMA gives ctx[q=lane][d = 4 consecutive per reg] -> packed
//   ds_write_b64 into ctx_lds[64][512] with 16B-slot XOR swizzle
//   (slot ^= row&7) to keep phase-B ds_read_b128 conflict-free.
// Phase B: out[64x512] = ctx @ w_out^T + b_out. Wave w owns n-cols w*64..+63;
//   w_out (512 KB bf16) streams from L2. acc[4][4], 256 MFMA/wave.
// LDS 64 KiB -> 2 blocks/CU, 16 waves/CU for latency hiding.
__global__ __launch_bounds__(512) void attn_out_kernel(
    const bf16* __restrict__ qkv, const bf16* __restrict__ woutb,
    const float* __restrict__ b_out, float* __restrict__ out)
{
  __shared__ __align__(16) bf16 ctx_lds[64][512];

  const int tid  = threadIdx.x;
  const int w    = tid >> 6;
  const int lane = tid & 63;
  const int l15  = lane & 15;
  const int kg   = lane >> 4;
  const size_t mbase = (size_t)blockIdx.x * 64;
  const int blk = w >> 1;
  const size_t rbase = mbase + blk * 16;

  // ---- phase A: attention, 4 heads per wave ----
#pragma unroll
  for (int hi = 0; hi < 4; ++hi) {
    const int h = (w & 1) * 4 + hi;
    const bf16* qp = qkv + (rbase + l15) * 1536 + h * 64 + kg * 8;
    short8 qf0 = *(const short8*)qp;
    short8 qf1 = *(const short8*)(qp + 32);
    short8 kf0 = *(const short8*)(qp + 512);
    short8 kf1 = *(const short8*)(qp + 544);

    // S[q=l15][k=kg*4+r] via swapped QK^T
    f32x4 st = (f32x4)0.f;
    st = __builtin_amdgcn_mfma_f32_16x16x32_bf16(kf0, qf0, st, 0, 0, 0);
    st = __builtin_amdgcn_mfma_f32_16x16x32_bf16(kf1, qf1, st, 0, 0, 0);

    float s[4];
#pragma unroll
    for (int r = 0; r < 4; ++r) s[r] = st[r] * 0.125f;  // 1/sqrt(64)
    float mx = fmaxf(fmaxf(s[0], s[1]), fmaxf(s[2], s[3]));
    mx = fmaxf(mx, __shfl_xor(mx, 16));
    mx = fmaxf(mx, __shfl_xor(mx, 32));
    float p[4], sum = 0.f;
#pragma unroll
    for (int r = 0; r < 4; ++r) { p[r] = __expf(s[r] - mx); sum += p[r]; }
    sum += __shfl_xor(sum, 16);
    sum += __shfl_xor(sum, 32);
    const float inv = 1.f / sum;

    short4v pf;  // P[q=l15][k=kg*4+r]
#pragma unroll
    for (int r = 0; r < 4; ++r) pf[r] = f2bf(p[r] * inv);

    const bf16* vp = qkv + rbase * 1536 + 1024 + h * 64;
#pragma unroll
    for (int dt = 0; dt < 4; ++dt) {
      short4v vf;
#pragma unroll
      for (int jj = 0; jj < 4; ++jj)
        vf[jj] = *(const short*)(vp + (size_t)(kg * 4 + jj) * 1536 + dt * 16 + l15);
      // swapped PV: lane holds ctx[q=l15][d = dt*16 + kg*4 + r]
      f32x4 c = (f32x4)0.f;
      c = __builtin_amdgcn_mfma_f32_16x16x16bf16_1k(vf, pf, c, 0, 0, 0);
      short4v o;
#pragma unroll
      for (int r = 0; r < 4; ++r) o[r] = f2bf(c[r]);
      // 16B-slot swizzled store: logical col c0 = h*64 + dt*16 + kg*4
      const int slot = h * 8 + dt * 2 + (kg >> 1);
      const int col  = ((slot ^ (l15 & 7)) << 3) | ((kg & 1) * 4);
      *(short4v*)&ctx_lds[blk * 16 + l15][col] = o;
    }
  }

  __syncthreads();

  // ---- phase B: out = ctx @ w_out^T + b_out ----
  f32x4 acc[4][4];
#pragma unroll
  for (int i = 0; i < 4; ++i)
#pragma unroll
    for (int j = 0; j < 4; ++j) acc[i][j] = (f32x4)0.f;

#pragma unroll
  for (int kc = 0; kc < 16; ++kc) {
    short8 wf[4], cf[4];
#pragma unroll
    for (int ni = 0; ni < 4; ++ni)
      wf[ni] = *(const short8*)&woutb[(size_t)(w * 64 + ni * 16 + l15) * 512 +
                                      kc * 32 + kg * 8];
#pragma unroll
    for (int mi = 0; mi < 4; ++mi) {
      const int row  = mi * 16 + l15;
      const int slot = kc * 4 + kg;
      cf[mi] = *(const short8*)&ctx_lds[row][((slot ^ (l15 & 7)) << 3)];
    }
#pragma unroll
    for (int mi = 0; mi < 4; ++mi)
#pragma unroll
      for (int ni = 0; ni < 4; ++ni)
        acc[mi][ni] = __builtin_amdgcn_mfma_f32_16x16x32_bf16(
            wf[ni], cf[mi], acc[mi][ni], 0, 0, 0);
  }

  // epilogue: m = mbase + mi*16 + l15, n = w*64 + ni*16 + kg*4 (+r)
#pragma unroll
  for (int mi = 0; mi < 4; ++mi) {
    const size_t mrow = mbase + mi * 16 + l15;
#pragma unroll
    for (int ni = 0; ni < 4; ++ni) {
      const int nb = w * 64 + ni * 16 + kg * 4;
      f32x4 bv = *(const f32x4*)&b_out[nb];
      *(f32x4*)&out[mrow * 512 + nb] = acc[mi][ni] + bv;
    }
  }
}

// ---------------- launch ----------------
extern "C" void kernel_launch(void* const* d_in, const int* in_sizes, int n_in,
                              void* d_out, int out_size, void* d_ws, size_t ws_size,
                              hipStream_t stream) {
  (void)in_sizes; (void)n_in; (void)out_size; (void)ws_size;
  const float* x     = (const float*)d_in[0];
  const float* w_in  = (const float*)d_in[1];
  const float* b_in  = (const float*)d_in[2];
  const float* w_out = (const float*)d_in[3];
  const float* b_out = (const float*)d_in[4];
  float* out = (float*)d_out;

  char* ws = (char*)d_ws;
  bf16* qkv   = (bf16*)ws;                                   // 65536*1536 bf16 = 201 MB
  bf16* winb  = (bf16*)(ws + (size_t)65536 * 1536 * 2);      // 1536*512
  bf16* woutb = (bf16*)(ws + (size_t)65536 * 1536 * 2 + (size_t)786432 * 2);
  // x in bf16 lives in d_out (67 MB in a 134 MB buffer) — the fused
  // attn+out kernel overwrites d_out afterwards and never reads xb.
  bf16* xb = (bf16*)d_out;

  cvt_f32_to_bf16<<<768, 256, 0, stream>>>(w_in, winb, 786432 / 4);
  cvt_f32_to_bf16<<<256, 256, 0, stream>>>(w_out, woutb, 262144 / 4);
  cvt_f32_to_bf16<<<4096, 256, 0, stream>>>(x, xb, (65536 * 512) / 4);

  // QKV = xb @ w_in^T + b_in  (M=65536, N=1536, K=512), bf16 out
  gemm_bt<true><<<1536, 512, 0, stream>>>(
      xb, 512, winb, 512, b_in, (void*)qkv, 1536, 6);

  // fused: block attention + out = ctx @ w_out^T + b_out (fp32)
  attn_out_kernel<<<1024, 512, 0, stream>>>(qkv, woutb, b_out, out);
}

// Round 8
// 294.259 us; speedup vs baseline: 1.0198x; 1.0198x over previous
//
#include <hip/hip_runtime.h>
#include <hip/hip_bf16.h>

typedef __attribute__((ext_vector_type(4))) float f32x4;
typedef __attribute__((ext_vector_type(8))) short short8;
typedef __attribute__((ext_vector_type(4))) short short4v;
using bf16 = __hip_bfloat16;

__device__ __forceinline__ short f2bf(float x) {
  union { bf16 h; short s; } u;
  u.h = __float2bfloat16(x);
  return u.s;
}

__device__ __forceinline__ void gload16(const void* g, void* l) {
  __builtin_amdgcn_global_load_lds(
      (const __attribute__((address_space(1))) void*)g,
      (__attribute__((address_space(3))) void*)l, 16, 0, 0);
}

// ---------------- fp32 -> bf16 conversion (grid-stride) ----------------
__global__ void cvt_f32_to_bf16(const float* __restrict__ src,
                                bf16* __restrict__ dst, int n4) {
  int i = blockIdx.x * blockDim.x + threadIdx.x;
  const int stride = gridDim.x * blockDim.x;
  for (; i < n4; i += stride) {
    f32x4 v = ((const f32x4*)src)[i];
    short4v o;
    o[0] = f2bf(v[0]); o[1] = f2bf(v[1]); o[2] = f2bf(v[2]); o[3] = f2bf(v[3]);
    ((short4v*)dst)[i] = o;
  }
}

// ------- 256x128 GEMM, BK=32, 3-buffer rotation, occupancy-first -------
// C = A * B^T + bias. K fixed 512 = 16 K-tiles, fully unrolled. 512 threads =
// 8 waves (4M x 2N), wave tile 64x64 -> acc[4][4] (64 AGPR) + ~56 VGPR frags
// => ~120 regs => 4 waves/SIMD. LDS 72 KiB (3 bufs x (A 256x32 + B 128x32))
// => 2 blocks/CU, 16 waves/CU: cross-block overlap (m114) hides per-block
// vmcnt/barrier stalls that capped the 1-block/CU r4 kernel at 683 TF.
//
// Rotation ledger: during tile t stage t+2 into buf (t+2)%3 == (t-1)%3
// (last read during t-1, barrier-separated -> no write-while-read). Close of
// tile t: counted vmcnt(3) -> all loads except t+2's 3 are complete -> tile
// t+1 fully resident. Tail: V(0) @ t=14.
template<bool OUT_BF16>
__global__ __launch_bounds__(512) void gemm_bt(
    const bf16* __restrict__ A, int lda,
    const bf16* __restrict__ B, int ldb,
    const float* __restrict__ bias,
    void* __restrict__ Cv, int ldc, int nbx)
{
  __shared__ __align__(16) bf16 lA[3][256 * 32];
  __shared__ __align__(16) bf16 lB[3][128 * 32];

  const int tid  = threadIdx.x;
  const int lane = tid & 63;
  const int w    = tid >> 6;   // wave 0..7
  const int mr   = w & 3;      // M quarter: rows mr*64..+63
  const int wn   = w >> 2;     // N half:    cols wn*64..+63
  const int l15  = lane & 15;
  const int kg   = lane >> 4;                    // k-slot 0..3
  const int po   = (kg ^ ((l15 >> 1) & 3)) * 8;  // swizzled read col (elems)

  const int nwg = gridDim.x;
  const int dd  = blockIdx.x;
  const int wid = (dd & 7) * (nwg >> 3) + (dd >> 3);  // bijective XCD swizzle
  const size_t bm = (size_t)(wid / nbx) * 256;
  const size_t bn = (size_t)(wid % nbx) * 128;

  // Staging: thread -> row w*16 + (lane>>2) (A: + h*128 for h=0,1), 16B at
  // source col-slot (lane&3)^((lane>>3)&3) [= logical ^ (row>>1)&3].
  // LDS dest is wave-uniform base + lane*16B (linear).
  const int srow = w * 16 + (lane >> 2);
  const int scol = ((lane & 3) ^ ((lane >> 3) & 3)) * 8;
  const int wofs = w * 512;

  const bf16* Ab = A + (bm + srow) * lda + scol;
  const bf16* Bb = B + (bn + srow) * ldb + scol;

  f32x4 acc[4][4];
#pragma unroll
  for (int i = 0; i < 4; ++i)
#pragma unroll
    for (int j = 0; j < 4; ++j) acc[i][j] = (f32x4)0.f;

  short8 af[4], bq[4];

  // stage one K-tile (3 gloads/thread): A rows 0-127, A rows 128-255, B
#define STG(buf, kt) do { \
    gload16(Ab + (size_t)(kt),             &lA[buf][wofs]); \
    gload16(Ab + (size_t)128 * lda + (kt), &lA[buf][4096 + wofs]); \
    gload16(Bb + (size_t)(kt),             &lB[buf][wofs]); } while (0)

#define CLOSE_V(N) do { \
    __builtin_amdgcn_sched_barrier(0); \
    asm volatile("s_waitcnt vmcnt(" #N ")" ::: "memory"); \
    __builtin_amdgcn_sched_barrier(0); \
    __builtin_amdgcn_s_barrier(); \
    __builtin_amdgcn_sched_barrier(0); \
    asm volatile("" ::: "memory"); } while (0)

  // prologue: stage tiles 0,1; wait t0 resident (t1 in flight)
  STG(0, 0);
  STG(1, 32);
  CLOSE_V(3);

#pragma unroll
  for (int t = 0; t < 16; ++t) {
    const int cur = t % 3;
    const int pf  = (t + 2) % 3;
    const int kt2 = (t + 2) * 32;

    // fragment reads from the stable current buffer (8 x ds_read_b128)
#pragma unroll
    for (int mi = 0; mi < 4; ++mi)
      af[mi] = *(const short8*)&lA[cur][(mr * 64 + mi * 16 + l15) * 32 + po];
#pragma unroll
    for (int ni = 0; ni < 4; ++ni)
      bq[ni] = *(const short8*)&lB[cur][(wn * 64 + ni * 16 + l15) * 32 + po];

    // stage tile t+2 (buf last read during t-1, barrier-separated)
    if (t < 14) STG(pf, kt2);

    __builtin_amdgcn_s_setprio(1);
#pragma unroll
    for (int mi = 0; mi < 4; ++mi)
#pragma unroll
      for (int ni = 0; ni < 4; ++ni)
        acc[mi][ni] = __builtin_amdgcn_mfma_f32_16x16x32_bf16(
            bq[ni], af[mi], acc[mi][ni], 0, 0, 0);
    __builtin_amdgcn_s_setprio(0);

    if (t <= 13)      CLOSE_V(3);
    else if (t == 14) CLOSE_V(0);
    // t == 15: fall through to epilogue
  }

#undef STG
#undef CLOSE_V

  // Epilogue: lane holds m = bm+mr*64+mi*16+l15, n = bn+wn*64+ni*16+kg*4+j
#pragma unroll
  for (int mi = 0; mi < 4; ++mi) {
    const size_t mrow = bm + mr * 64 + mi * 16 + l15;
#pragma unroll
    for (int ni = 0; ni < 4; ++ni) {
      const int nb = (int)bn + wn * 64 + ni * 16 + kg * 4;
      f32x4 bv = *(const f32x4*)&bias[nb];
      f32x4 r = acc[mi][ni] + bv;
      if constexpr (OUT_BF16) {
        short4v o;
        o[0] = f2bf(r[0]); o[1] = f2bf(r[1]); o[2] = f2bf(r[2]); o[3] = f2bf(r[3]);
        *(short4v*)((bf16*)Cv + mrow * ldc + nb) = o;
      } else {
        *(f32x4*)((float*)Cv + mrow * ldc + nb) = r;
      }
    }
  }
}

// ------------- fused block-attention + output GEMM -------------
// One block per 64 qkv rows (4 attention 16-blocks). 512 threads = 8 waves.
// Phase A: wave w handles 16-row sub-block (w>>1) x heads (w&1)*4..+3.
//   Swapped-PV MFMA gives ctx[q=lane][d = 4 consecutive per reg] -> packed
//   ds_write_b64 into ctx_lds[64][512] with 16B-slot XOR swizzle
//   (slot ^= row&7) to keep phase-B ds_read_b128 conflict-free.
// Phase B: out[64x512] = ctx @ w_out^T + b_out. Wave w owns n-cols w*64..+63;
//   w_out (512 KB bf16) streams from L2. acc[4][4], 256 MFMA/wave.
// LDS 64 KiB -> 2 blocks/CU, 16 waves/CU for latency hiding.
__global__ __launch_bounds__(512) void attn_out_kernel(
    const bf16* __restrict__ qkv, const bf16* __restrict__ woutb,
    const float* __restrict__ b_out, float* __restrict__ out)
{
  __shared__ __align__(16) bf16 ctx_lds[64][512];

  const int tid  = threadIdx.x;
  const int w    = tid >> 6;
  const int lane = tid & 63;
  const int l15  = lane & 15;
  const int kg   = lane >> 4;
  const size_t mbase = (size_t)blockIdx.x * 64;
  const int blk = w >> 1;
  const size_t rbase = mbase + blk * 16;

  // ---- phase A: attention, 4 heads per wave ----
#pragma unroll
  for (int hi = 0; hi < 4; ++hi) {
    const int h = (w & 1) * 4 + hi;
    const bf16* qp = qkv + (rbase + l15) * 1536 + h * 64 + kg * 8;
    short8 qf0 = *(const short8*)qp;
    short8 qf1 = *(const short8*)(qp + 32);
    short8 kf0 = *(const short8*)(qp + 512);
    short8 kf1 = *(const short8*)(qp + 544);

    // S[q=l15][k=kg*4+r] via swapped QK^T
    f32x4 st = (f32x4)0.f;
    st = __builtin_amdgcn_mfma_f32_16x16x32_bf16(kf0, qf0, st, 0, 0, 0);
    st = __builtin_amdgcn_mfma_f32_16x16x32_bf16(kf1, qf1, st, 0, 0, 0);

    float s[4];
#pragma unroll
    for (int r = 0; r < 4; ++r) s[r] = st[r] * 0.125f;  // 1/sqrt(64)
    float mx = fmaxf(fmaxf(s[0], s[1]), fmaxf(s[2], s[3]));
    mx = fmaxf(mx, __shfl_xor(mx, 16));
    mx = fmaxf(mx, __shfl_xor(mx, 32));
    float p[4], sum = 0.f;
#pragma unroll
    for (int r = 0; r < 4; ++r) { p[r] = __expf(s[r] - mx); sum += p[r]; }
    sum += __shfl_xor(sum, 16);
    sum += __shfl_xor(sum, 32);
    const float inv = 1.f / sum;

    short4v pf;  // P[q=l15][k=kg*4+r]
#pragma unroll
    for (int r = 0; r < 4; ++r) pf[r] = f2bf(p[r] * inv);

    const bf16* vp = qkv + rbase * 1536 + 1024 + h * 64;
#pragma unroll
    for (int dt = 0; dt < 4; ++dt) {
      short4v vf;
#pragma unroll
      for (int jj = 0; jj < 4; ++jj)
        vf[jj] = *(const short*)(vp + (size_t)(kg * 4 + jj) * 1536 + dt * 16 + l15);
      // swapped PV: lane holds ctx[q=l15][d = dt*16 + kg*4 + r]
      f32x4 c = (f32x4)0.f;
      c = __builtin_amdgcn_mfma_f32_16x16x16bf16_1k(vf, pf, c, 0, 0, 0);
      short4v o;
#pragma unroll
      for (int r = 0; r < 4; ++r) o[r] = f2bf(c[r]);
      // 16B-slot swizzled store: logical col c0 = h*64 + dt*16 + kg*4
      const int slot = h * 8 + dt * 2 + (kg >> 1);
      const int col  = ((slot ^ (l15 & 7)) << 3) | ((kg & 1) * 4);
      *(short4v*)&ctx_lds[blk * 16 + l15][col] = o;
    }
  }

  __syncthreads();

  // ---- phase B: out = ctx @ w_out^T + b_out ----
  f32x4 acc[4][4];
#pragma unroll
  for (int i = 0; i < 4; ++i)
#pragma unroll
    for (int j = 0; j < 4; ++j) acc[i][j] = (f32x4)0.f;

#pragma unroll
  for (int kc = 0; kc < 16; ++kc) {
    short8 wf[4], cf[4];
#pragma unroll
    for (int ni = 0; ni < 4; ++ni)
      wf[ni] = *(const short8*)&woutb[(size_t)(w * 64 + ni * 16 + l15) * 512 +
                                      kc * 32 + kg * 8];
#pragma unroll
    for (int mi = 0; mi < 4; ++mi) {
      const int row  = mi * 16 + l15;
      const int slot = kc * 4 + kg;
      cf[mi] = *(const short8*)&ctx_lds[row][((slot ^ (l15 & 7)) << 3)];
    }
#pragma unroll
    for (int mi = 0; mi < 4; ++mi)
#pragma unroll
      for (int ni = 0; ni < 4; ++ni)
        acc[mi][ni] = __builtin_amdgcn_mfma_f32_16x16x32_bf16(
            wf[ni], cf[mi], acc[mi][ni], 0, 0, 0);
  }

  // epilogue: m = mbase + mi*16 + l15, n = w*64 + ni*16 + kg*4 (+r)
#pragma unroll
  for (int mi = 0; mi < 4; ++mi) {
    const size_t mrow = mbase + mi * 16 + l15;
#pragma unroll
    for (int ni = 0; ni < 4; ++ni) {
      const int nb = w * 64 + ni * 16 + kg * 4;
      f32x4 bv = *(const f32x4*)&b_out[nb];
      *(f32x4*)&out[mrow * 512 + nb] = acc[mi][ni] + bv;
    }
  }
}

// ---------------- launch ----------------
extern "C" void kernel_launch(void* const* d_in, const int* in_sizes, int n_in,
                              void* d_out, int out_size, void* d_ws, size_t ws_size,
                              hipStream_t stream) {
  (void)in_sizes; (void)n_in; (void)out_size; (void)ws_size;
  const float* x     = (const float*)d_in[0];
  const float* w_in  = (const float*)d_in[1];
  const float* b_in  = (const float*)d_in[2];
  const float* w_out = (const float*)d_in[3];
  const float* b_out = (const float*)d_in[4];
  float* out = (float*)d_out;

  char* ws = (char*)d_ws;
  bf16* qkv   = (bf16*)ws;                                   // 65536*1536 bf16 = 201 MB
  bf16* winb  = (bf16*)(ws + (size_t)65536 * 1536 * 2);      // 1536*512
  bf16* woutb = (bf16*)(ws + (size_t)65536 * 1536 * 2 + (size_t)786432 * 2);
  // x in bf16 lives in d_out (67 MB in a 134 MB buffer) — the fused
  // attn+out kernel overwrites d_out afterwards and never reads xb.
  bf16* xb = (bf16*)d_out;

  cvt_f32_to_bf16<<<768, 256, 0, stream>>>(w_in, winb, 786432 / 4);
  cvt_f32_to_bf16<<<256, 256, 0, stream>>>(w_out, woutb, 262144 / 4);
  cvt_f32_to_bf16<<<4096, 256, 0, stream>>>(x, xb, (65536 * 512) / 4);

  // QKV = xb @ w_in^T + b_in  (M=65536, N=1536, K=512), bf16 out
  gemm_bt<true><<<3072, 512, 0, stream>>>(
      xb, 512, winb, 512, b_in, (void*)qkv, 1536, 12);

  // fused: block attention + out = ctx @ w_out^T + b_out (fp32)
  attn_out_kernel<<<1024, 512, 0, stream>>>(qkv, woutb, b_out, out);
}

// Round 9
// 293.952 us; speedup vs baseline: 1.0209x; 1.0010x over previous
//
#include <hip/hip_runtime.h>
#include <hip/hip_bf16.h>

typedef __attribute__((ext_vector_type(4))) float f32x4;
typedef __attribute__((ext_vector_type(8))) short short8;
typedef __attribute__((ext_vector_type(4))) short short4v;
using bf16 = __hip_bfloat16;

__device__ __forceinline__ short f2bf(float x) {
  union { bf16 h; short s; } u;
  u.h = __float2bfloat16(x);
  return u.s;
}

__device__ __forceinline__ void gload16(const void* g, void* l) {
  __builtin_amdgcn_global_load_lds(
      (const __attribute__((address_space(1))) void*)g,
      (__attribute__((address_space(3))) void*)l, 16, 0, 0);
}

// ---------------- fp32 -> bf16 conversion (grid-stride) ----------------
__global__ void cvt_f32_to_bf16(const float* __restrict__ src,
                                bf16* __restrict__ dst, int n4) {
  int i = blockIdx.x * blockDim.x + threadIdx.x;
  const int stride = gridDim.x * blockDim.x;
  for (; i < n4; i += stride) {
    f32x4 v = ((const f32x4*)src)[i];
    short4v o;
    o[0] = f2bf(v[0]); o[1] = f2bf(v[1]); o[2] = f2bf(v[2]); o[3] = f2bf(v[3]);
    ((short4v*)dst)[i] = o;
  }
}

// ------- 256x128 GEMM, BK=32, 3-buffer rotation (r8-frozen, 683 TF) -------
// C = A * B^T + bias. K fixed 512 = 16 K-tiles, fully unrolled. 512 threads =
// 8 waves (4M x 2N), wave tile 64x64 -> acc[4][4]. LDS 72 KiB.
// Rotation ledger: during tile t stage t+2 into buf (t+2)%3 == (t-1)%3
// (last read during t-1, barrier-separated). Close of tile t: counted
// vmcnt(3) -> tile t+1 fully resident. Tail: V(0) @ t=14.
template<bool OUT_BF16>
__global__ __launch_bounds__(512) void gemm_bt(
    const bf16* __restrict__ A, int lda,
    const bf16* __restrict__ B, int ldb,
    const float* __restrict__ bias,
    void* __restrict__ Cv, int ldc, int nbx)
{
  __shared__ __align__(16) bf16 lA[3][256 * 32];
  __shared__ __align__(16) bf16 lB[3][128 * 32];

  const int tid  = threadIdx.x;
  const int lane = tid & 63;
  const int w    = tid >> 6;   // wave 0..7
  const int mr   = w & 3;      // M quarter: rows mr*64..+63
  const int wn   = w >> 2;     // N half:    cols wn*64..+63
  const int l15  = lane & 15;
  const int kg   = lane >> 4;                    // k-slot 0..3
  const int po   = (kg ^ ((l15 >> 1) & 3)) * 8;  // swizzled read col (elems)

  const int nwg = gridDim.x;
  const int dd  = blockIdx.x;
  const int wid = (dd & 7) * (nwg >> 3) + (dd >> 3);  // bijective XCD swizzle
  const size_t bm = (size_t)(wid / nbx) * 256;
  const size_t bn = (size_t)(wid % nbx) * 128;

  const int srow = w * 16 + (lane >> 2);
  const int scol = ((lane & 3) ^ ((lane >> 3) & 3)) * 8;
  const int wofs = w * 512;

  const bf16* Ab = A + (bm + srow) * lda + scol;
  const bf16* Bb = B + (bn + srow) * ldb + scol;

  f32x4 acc[4][4];
#pragma unroll
  for (int i = 0; i < 4; ++i)
#pragma unroll
    for (int j = 0; j < 4; ++j) acc[i][j] = (f32x4)0.f;

  short8 af[4], bq[4];

#define STG(buf, kt) do { \
    gload16(Ab + (size_t)(kt),             &lA[buf][wofs]); \
    gload16(Ab + (size_t)128 * lda + (kt), &lA[buf][4096 + wofs]); \
    gload16(Bb + (size_t)(kt),             &lB[buf][wofs]); } while (0)

#define CLOSE_V(N) do { \
    __builtin_amdgcn_sched_barrier(0); \
    asm volatile("s_waitcnt vmcnt(" #N ")" ::: "memory"); \
    __builtin_amdgcn_sched_barrier(0); \
    __builtin_amdgcn_s_barrier(); \
    __builtin_amdgcn_sched_barrier(0); \
    asm volatile("" ::: "memory"); } while (0)

  STG(0, 0);
  STG(1, 32);
  CLOSE_V(3);

#pragma unroll
  for (int t = 0; t < 16; ++t) {
    const int cur = t % 3;
    const int pf  = (t + 2) % 3;
    const int kt2 = (t + 2) * 32;

#pragma unroll
    for (int mi = 0; mi < 4; ++mi)
      af[mi] = *(const short8*)&lA[cur][(mr * 64 + mi * 16 + l15) * 32 + po];
#pragma unroll
    for (int ni = 0; ni < 4; ++ni)
      bq[ni] = *(const short8*)&lB[cur][(wn * 64 + ni * 16 + l15) * 32 + po];

    if (t < 14) STG(pf, kt2);

    __builtin_amdgcn_s_setprio(1);
#pragma unroll
    for (int mi = 0; mi < 4; ++mi)
#pragma unroll
      for (int ni = 0; ni < 4; ++ni)
        acc[mi][ni] = __builtin_amdgcn_mfma_f32_16x16x32_bf16(
            bq[ni], af[mi], acc[mi][ni], 0, 0, 0);
    __builtin_amdgcn_s_setprio(0);

    if (t <= 13)      CLOSE_V(3);
    else if (t == 14) CLOSE_V(0);
  }

#undef STG
#undef CLOSE_V

#pragma unroll
  for (int mi = 0; mi < 4; ++mi) {
    const size_t mrow = bm + mr * 64 + mi * 16 + l15;
#pragma unroll
    for (int ni = 0; ni < 4; ++ni) {
      const int nb = (int)bn + wn * 64 + ni * 16 + kg * 4;
      f32x4 bv = *(const f32x4*)&bias[nb];
      f32x4 r = acc[mi][ni] + bv;
      if constexpr (OUT_BF16) {
        short4v o;
        o[0] = f2bf(r[0]); o[1] = f2bf(r[1]); o[2] = f2bf(r[2]); o[3] = f2bf(r[3]);
        *(short4v*)((bf16*)Cv + mrow * ldc + nb) = o;
      } else {
        *(f32x4*)((float*)Cv + mrow * ldc + nb) = r;
      }
    }
  }
}

// ------------- fused block-attention + output GEMM -------------
// One block per 64 qkv rows. 512 threads = 8 waves; wave w owns attention
// sub-block blk=w>>1 (16 rows) x heads (w&1)*4..+3, and phase-B cols w*64..+63.
//
// buf[64][520] (65 KB, +8-elem row pad for bank stagger) serves two lives:
//  1. V-strip (rows 0..63 = qkv V region cols 0..511), staged coalesced via
//     global_load_lds (8 per wave). vf gather becomes ds_read_u16 (<=2-way
//     aliasing = free) instead of 64 scalar GLOBAL loads per lane.
//  2. ctx: each wave's ctx columns == its own V columns, so ctx overwrites V
//     in-place per head AFTER that head's PV (read->MFMA->write dep chain,
//     same-wave in-order LDS => race-free; no extra barriers).
// Phase B: out = ctx @ w_out^T + b_out; 520-stride staggers rows so b128
// reads hit bank quartets uniformly (no XOR swizzle needed).
__global__ __launch_bounds__(512) void attn_out_kernel(
    const bf16* __restrict__ qkv, const bf16* __restrict__ woutb,
    const float* __restrict__ b_out, float* __restrict__ out)
{
  __shared__ __align__(16) bf16 buf[64][520];

  const int tid  = threadIdx.x;
  const int w    = tid >> 6;
  const int lane = tid & 63;
  const int l15  = lane & 15;
  const int kg   = lane >> 4;
  const size_t mbase = (size_t)blockIdx.x * 64;
  const int blk = w >> 1;
  const size_t rbase = mbase + blk * 16;

  // ---- stage V strip: wave w stages rows w*8..+7, 1024B per row ----
  {
    const bf16* vsrc = qkv + 1024 + (size_t)lane * 8;  // per-lane 16B src
#pragma unroll
    for (int i = 0; i < 8; ++i) {
      const int row = w * 8 + i;
      gload16(vsrc + (mbase + row) * 1536, &buf[row][0]);
    }
  }
  __syncthreads();  // drains vmcnt (compiler-inserted before s_barrier)

  // ---- phase A: attention, 4 heads per wave; ctx overwrites own V ----
#pragma unroll
  for (int hi = 0; hi < 4; ++hi) {
    const int h = (w & 1) * 4 + hi;
    const bf16* qp = qkv + (rbase + l15) * 1536 + h * 64 + kg * 8;
    short8 qf0 = *(const short8*)qp;
    short8 qf1 = *(const short8*)(qp + 32);
    short8 kf0 = *(const short8*)(qp + 512);
    short8 kf1 = *(const short8*)(qp + 544);

    // S[q=l15][k=kg*4+r] via swapped QK^T
    f32x4 st = (f32x4)0.f;
    st = __builtin_amdgcn_mfma_f32_16x16x32_bf16(kf0, qf0, st, 0, 0, 0);
    st = __builtin_amdgcn_mfma_f32_16x16x32_bf16(kf1, qf1, st, 0, 0, 0);

    float s[4];
#pragma unroll
    for (int r = 0; r < 4; ++r) s[r] = st[r] * 0.125f;  // 1/sqrt(64)
    float mx = fmaxf(fmaxf(s[0], s[1]), fmaxf(s[2], s[3]));
    mx = fmaxf(mx, __shfl_xor(mx, 16));
    mx = fmaxf(mx, __shfl_xor(mx, 32));
    float p[4], sum = 0.f;
#pragma unroll
    for (int r = 0; r < 4; ++r) { p[r] = __expf(s[r] - mx); sum += p[r]; }
    sum += __shfl_xor(sum, 16);
    sum += __shfl_xor(sum, 32);
    const float inv = 1.f / sum;

    short4v pf;  // P[q=l15][k=kg*4+r]
#pragma unroll
    for (int r = 0; r < 4; ++r) pf[r] = f2bf(p[r] * inv);

#pragma unroll
    for (int dt = 0; dt < 4; ++dt) {
      short4v vf;  // A-frag: lane holds V[k=kg*4+jj][d=dt*16+l15]
#pragma unroll
      for (int jj = 0; jj < 4; ++jj)
        vf[jj] = *(const short*)&buf[blk * 16 + kg * 4 + jj][h * 64 + dt * 16 + l15];
      // swapped PV: lane holds ctx[q=l15][d = dt*16 + kg*4 + r]
      f32x4 c = (f32x4)0.f;
      c = __builtin_amdgcn_mfma_f32_16x16x16bf16_1k(vf, pf, c, 0, 0, 0);
      short4v o;
#pragma unroll
      for (int r = 0; r < 4; ++r) o[r] = f2bf(c[r]);
      // overwrite this head's (now-consumed) V columns with ctx
      *(short4v*)&buf[blk * 16 + l15][h * 64 + dt * 16 + kg * 4] = o;
    }
  }

  __syncthreads();

  // ---- phase B: out = ctx @ w_out^T + b_out ----
  f32x4 acc[4][4];
#pragma unroll
  for (int i = 0; i < 4; ++i)
#pragma unroll
    for (int j = 0; j < 4; ++j) acc[i][j] = (f32x4)0.f;

#pragma unroll
  for (int kc = 0; kc < 16; ++kc) {
    short8 wf[4], cf[4];
#pragma unroll
    for (int ni = 0; ni < 4; ++ni)
      wf[ni] = *(const short8*)&woutb[(size_t)(w * 64 + ni * 16 + l15) * 512 +
                                      kc * 32 + kg * 8];
#pragma unroll
    for (int mi = 0; mi < 4; ++mi)
      cf[mi] = *(const short8*)&buf[mi * 16 + l15][kc * 32 + kg * 8];
#pragma unroll
    for (int mi = 0; mi < 4; ++mi)
#pragma unroll
      for (int ni = 0; ni < 4; ++ni)
        acc[mi][ni] = __builtin_amdgcn_mfma_f32_16x16x32_bf16(
            wf[ni], cf[mi], acc[mi][ni], 0, 0, 0);
  }

  // epilogue: m = mbase + mi*16 + l15, n = w*64 + ni*16 + kg*4 (+r)
#pragma unroll
  for (int mi = 0; mi < 4; ++mi) {
    const size_t mrow = mbase + mi * 16 + l15;
#pragma unroll
    for (int ni = 0; ni < 4; ++ni) {
      const int nb = w * 64 + ni * 16 + kg * 4;
      f32x4 bv = *(const f32x4*)&b_out[nb];
      *(f32x4*)&out[mrow * 512 + nb] = acc[mi][ni] + bv;
    }
  }
}

// ---------------- launch ----------------
extern "C" void kernel_launch(void* const* d_in, const int* in_sizes, int n_in,
                              void* d_out, int out_size, void* d_ws, size_t ws_size,
                              hipStream_t stream) {
  (void)in_sizes; (void)n_in; (void)out_size; (void)ws_size;
  const float* x     = (const float*)d_in[0];
  const float* w_in  = (const float*)d_in[1];
  const float* b_in  = (const float*)d_in[2];
  const float* w_out = (const float*)d_in[3];
  const float* b_out = (const float*)d_in[4];
  float* out = (float*)d_out;

  char* ws = (char*)d_ws;
  bf16* qkv   = (bf16*)ws;                                   // 65536*1536 bf16 = 201 MB
  bf16* winb  = (bf16*)(ws + (size_t)65536 * 1536 * 2);      // 1536*512
  bf16* woutb = (bf16*)(ws + (size_t)65536 * 1536 * 2 + (size_t)786432 * 2);
  // x in bf16 lives in d_out (67 MB in a 134 MB buffer) — the fused
  // attn+out kernel overwrites d_out afterwards and never reads xb.
  bf16* xb = (bf16*)d_out;

  cvt_f32_to_bf16<<<768, 256, 0, stream>>>(w_in, winb, 786432 / 4);
  cvt_f32_to_bf16<<<256, 256, 0, stream>>>(w_out, woutb, 262144 / 4);
  cvt_f32_to_bf16<<<4096, 256, 0, stream>>>(x, xb, (65536 * 512) / 4);

  // QKV = xb @ w_in^T + b_in  (M=65536, N=1536, K=512), bf16 out
  gemm_bt<true><<<3072, 512, 0, stream>>>(
      xb, 512, winb, 512, b_in, (void*)qkv, 1536, 12);

  // fused: block attention + out = ctx @ w_out^T + b_out (fp32)
  attn_out_kernel<<<1024, 512, 0, stream>>>(qkv, woutb, b_out, out);
}